// Round 1
// baseline (477.233 us; speedup 1.0000x reference)
//
#include <hip/hip_runtime.h>
#include <hip/hip_cooperative_groups.h>

// Per-image standardization, input (64, 512, 512, 3) fp32.
// Fused single cooperative kernel:
//   phase 1: per-block {sum, sumsq} partials (coalesced float4 reads)
//   grid.sync()
//   phase 2: per-image mean/inv-std, normalize chunk (L3-served re-read),
//            non-temporal stores so the write stream doesn't thrash L3.
//
// Geometry: 64 images x 16 blocks/image = 1024 blocks x 256 threads.
// __launch_bounds__(256, 4) caps VGPR at 128 -> 4 blocks/CU guaranteed
// co-resident (1024 == 256 CU x 4), so the cooperative launch cannot fail
// for occupancy reasons.

#define N_IMG 64
#define ELEMS_PER_IMG 786432
#define VEC4_PER_IMG 196608
#define BLOCKS_PER_IMG 16
#define GRID (N_IMG * BLOCKS_PER_IMG)                    // 1024
#define THREADS 256
#define VEC4_PER_BLOCK (VEC4_PER_IMG / BLOCKS_PER_IMG)   // 12288
#define VEC4_PER_THREAD (VEC4_PER_BLOCK / THREADS)       // 48

typedef float v4f __attribute__((ext_vector_type(4)));

namespace cg = cooperative_groups;

__global__ __launch_bounds__(THREADS, 4) void std_fused(
    const v4f* __restrict__ in, v4f* __restrict__ out,
    float2* __restrict__ partials) {
    const int img = blockIdx.x / BLOCKS_PER_IMG;
    const int blk = blockIdx.x % BLOCKS_PER_IMG;
    const size_t base =
        (size_t)img * VEC4_PER_IMG + (size_t)blk * VEC4_PER_BLOCK;
    const v4f* __restrict__ bin = in + base;

    // ---- phase 1: partial {sum, sumsq} for this block's chunk ----
    float s = 0.f, sq = 0.f;
#pragma unroll 8
    for (int i = 0; i < VEC4_PER_THREAD; ++i) {
        v4f v = bin[threadIdx.x + i * THREADS];
        s += (v.x + v.y) + (v.z + v.w);
        sq = fmaf(v.x, v.x, sq);
        sq = fmaf(v.y, v.y, sq);
        sq = fmaf(v.z, v.z, sq);
        sq = fmaf(v.w, v.w, sq);
    }

#pragma unroll
    for (int off = 32; off > 0; off >>= 1) {
        s += __shfl_down(s, off);
        sq += __shfl_down(sq, off);
    }
    __shared__ float ss[4], ssq[4];
    const int lane = threadIdx.x & 63;
    const int wave = threadIdx.x >> 6;
    if (lane == 0) { ss[wave] = s; ssq[wave] = sq; }
    __syncthreads();
    if (threadIdx.x == 0) {
        float2 p;
        p.x = (ss[0] + ss[1]) + (ss[2] + ss[3]);
        p.y = (ssq[0] + ssq[1]) + (ssq[2] + ssq[3]);
        partials[blockIdx.x] = p;
    }

    // ---- grid-wide barrier: all partials visible everywhere ----
    cg::this_grid().sync();

    // ---- phase 2: reduce this image's 16 partials, normalize chunk ----
    __shared__ float s_mean, s_inv;
    if (threadIdx.x < 64) {
        float ps = 0.f, psq = 0.f;
        if (threadIdx.x < BLOCKS_PER_IMG) {
            float2 p = partials[img * BLOCKS_PER_IMG + threadIdx.x];
            ps = p.x;
            psq = p.y;
        }
#pragma unroll
        for (int off = 8; off > 0; off >>= 1) {
            ps += __shfl_down(ps, off);
            psq += __shfl_down(psq, off);
        }
        if (threadIdx.x == 0) {
            const float invN = 1.0f / (float)ELEMS_PER_IMG;
            float mean = ps * invN;
            float var = fmaxf(psq * invN - mean * mean, 0.0f);
            float sd = sqrtf(var);
            float min_sd = 1.0f / sqrtf((float)ELEMS_PER_IMG);  // TF clamp
            sd = fmaxf(sd, min_sd);
            s_mean = mean;
            s_inv = 1.0f / sd;
        }
    }
    __syncthreads();
    const float mean = s_mean;
    const float inv = s_inv;

    v4f* __restrict__ bout = out + base;
#pragma unroll 8
    for (int i = 0; i < VEC4_PER_THREAD; ++i) {
        const int idx = threadIdx.x + i * THREADS;
        v4f v = bin[idx];  // L2/L3-served: phase 1 just streamed this
        v4f r;
        r.x = (v.x - mean) * inv;
        r.y = (v.y - mean) * inv;
        r.z = (v.z - mean) * inv;
        r.w = (v.w - mean) * inv;
        __builtin_nontemporal_store(r, &bout[idx]);
    }
}

extern "C" void kernel_launch(void* const* d_in, const int* in_sizes, int n_in,
                              void* d_out, int out_size, void* d_ws, size_t ws_size,
                              hipStream_t stream) {
    const v4f* in = (const v4f*)d_in[0];
    v4f* out = (v4f*)d_out;
    float2* partials = (float2*)d_ws;  // 1024 x float2 = 8 KiB

    void* args[] = {(void*)&in, (void*)&out, (void*)&partials};
    hipLaunchCooperativeKernel((const void*)std_fused, dim3(GRID),
                               dim3(THREADS), args, 0, stream);
}